// Round 5
// baseline (31747.443 us; speedup 1.0000x reference)
//
#include <hip/hip_runtime.h>
#include <math.h>

// ---------------- problem constants ----------------
constexpr int MM = 8;      // batch of GPs
constexpr int NC = 1024;   // context points
constexpr int NT = 512;    // target points

// Workspace (floats):
//  Kb   : MM*1024*1024   (K raw/Schur -> G = K^-1 after syrk)
//  Ab   : MM*1024*1024   (diag-block inverses + L panels -> A = L^-1)
//  Tb   : MM*512*512     (trinv temp; S1/S2 at predict)
//  Ktc  : MM*NT*NC
//  alpha: MM*1024
//  acc  : MM*8  (two sets of [T1,T2,trG,pad], double-buffered by step parity)
//  bar  : MM*128 u32 (per-m barrier: 4 counters @0/16/32/48, root @64, gen @80)
constexpr size_t OFF_A     = (size_t)MM * 1024 * 1024;
constexpr size_t OFF_T     = OFF_A * 2;
constexpr size_t OFF_KTC   = OFF_T + (size_t)MM * 512 * 512;
constexpr size_t OFF_ALPHA = OFF_KTC + (size_t)MM * NT * NC;
constexpr size_t OFF_ACC   = OFF_ALPHA + (size_t)MM * 1024;
constexpr size_t OFF_BAR   = OFF_ACC + (size_t)MM * 8;

#define S5 2.2360679775f

__device__ __forceinline__ float sigmf(float x) { return 1.0f / (1.0f + expf(-x)); }
__device__ __forceinline__ float softplusf(float x) { return fmaxf(x, 0.0f) + log1pf(expf(-fabsf(x))); }

__device__ __forceinline__ void lt_decode(int x, int& i, int& j) {
  int ii = 0;
  while ((ii + 1) * (ii + 2) / 2 <= x) ++ii;
  i = ii; j = x - ii * (ii + 1) / 2;
}

// Shared-memory struct (~47.5 KB -> 3 blocks/CU)
struct SMem {
  float Ls[64 * 65];
  float Us[64 * 65];
  float Tt[32 * 33];
  float dvec[64];
  float As[16][68];
  float Bs[16][68];
  float xi[64][3];
  float xj[64][3];
  float ai[64];
  float aj[64];
  float red[4][4];
};

// ---------------- per-m grid barrier ----------------------------------------
// KEY FIX vs r4: poll via atomic RMW at SYSTEM scope. RMW executes at the
// coherence point (LLC) -> always-fresh value in ~1us, no cache invalidation.
// r4's relaxed plain-load poll waited on random L2 eviction (35-66ms variance);
// r3's acquire poll invalidated L2 every ~700cy (FETCH 7x). One threadfence
// after exit provides acquire ordering.
__device__ __forceinline__ void gbar(unsigned* barm, int lb, unsigned per, int& epoch) {
  __syncthreads();
  if (threadIdx.x == 0) {
    unsigned e1 = (unsigned)(epoch + 1);
    __threadfence();  // release: make this block's writes agent-visible
    unsigned* ctr = barm + ((lb & 3) << 4);  // 64B-padded sub-counters
    unsigned old = __hip_atomic_fetch_add(ctr, 1u, __ATOMIC_RELAXED, __HIP_MEMORY_SCOPE_AGENT);
    if (old + 1u == per * e1) {
      unsigned r = __hip_atomic_fetch_add(barm + 64, 1u, __ATOMIC_RELAXED, __HIP_MEMORY_SCOPE_AGENT);
      if (r + 1u == 4u * e1) {
        __hip_atomic_store(barm + 80, e1, __ATOMIC_RELEASE, __HIP_MEMORY_SCOPE_SYSTEM);
      }
    }
    while (__hip_atomic_fetch_add(barm + 80, 0u, __ATOMIC_RELAXED, __HIP_MEMORY_SCOPE_SYSTEM) < e1) {
      __builtin_amdgcn_s_sleep(8);
    }
    __threadfence();  // acquire: one invalidate per barrier, not per poll
  }
  __syncthreads();
  epoch += 1;
}

// ---------------- 64x64-tile GEMM, register-prefetch double-buffered ---------
template <int TA, int TB>
__device__ __forceinline__ void gemm64(const float* __restrict__ A, int lda,
                                       const float* __restrict__ B, int ldb,
                                       int kBeg, int kEnd, float acc[4][4], SMem& sm) {
  int tid = threadIdx.x, tx = tid & 15, ty = tid >> 4;
  float ra[4], rb[4];
  auto ldAB = [&](int k0) {
#pragma unroll
    for (int q = 0; q < 4; ++q) {
      int e = tid + (q << 8);
      if (TA) { int kk = e >> 6, r = e & 63; ra[q] = A[(size_t)(k0 + kk) * lda + r]; }
      else    { int r = e >> 4, kk = e & 15; ra[q] = A[(size_t)r * lda + k0 + kk]; }
      if (TB) { int c = e >> 4, kk = e & 15; rb[q] = B[(size_t)c * ldb + k0 + kk]; }
      else    { int kk = e >> 6, c = e & 63; rb[q] = B[(size_t)(k0 + kk) * ldb + c]; }
    }
  };
  ldAB(kBeg);
  for (int k0 = kBeg; k0 < kEnd; k0 += 16) {
    __syncthreads();
#pragma unroll
    for (int q = 0; q < 4; ++q) {
      int e = tid + (q << 8);
      if (TA) sm.As[e >> 6][e & 63] = ra[q]; else sm.As[e & 15][e >> 4] = ra[q];
      if (TB) sm.Bs[e & 15][e >> 4] = rb[q]; else sm.Bs[e >> 6][e & 63] = rb[q];
    }
    __syncthreads();
    if (k0 + 16 < kEnd) ldAB(k0 + 16);
#pragma unroll
    for (int kk = 0; kk < 16; ++kk) {
      float a[4], b[4];
#pragma unroll
      for (int i = 0; i < 4; ++i) a[i] = sm.As[kk][ty * 4 + i];
#pragma unroll
      for (int j = 0; j < 4; ++j) b[j] = sm.Bs[kk][tx * 4 + j];
#pragma unroll
      for (int i = 0; i < 4; ++i)
#pragma unroll
        for (int j = 0; j < 4; ++j) acc[i][j] = fmaf(a[i], b[j], acc[i][j]);
    }
  }
}

// ---------------- in-LDS 64x64 SPD factor + triangular inverse ---------------
__device__ void factor64(SMem& sm, float* Uout, int ldu) {
  int tid = threadIdx.x;
  int tx = tid & 15, ty = tid >> 4;
  for (int j = 0; j < 63; ++j) {
    float rinv = 1.0f / sm.Ls[j * 65 + j];
    for (int i = j + 1 + ty; i < 64; i += 16) {
      float lij = sm.Ls[i * 65 + j] * rinv;
      for (int c = j + 1 + tx; c <= i; c += 16) sm.Ls[i * 65 + c] -= lij * sm.Ls[c * 65 + j];
    }
    __syncthreads();
  }
  if (tid < 64) sm.dvec[tid] = 1.0f / sqrtf(sm.Ls[tid * 65 + tid]);
  __syncthreads();
  for (int e = tid; e < 4096; e += 256) { int r = e >> 6, c = e & 63; if (c <= r) sm.Ls[r * 65 + c] *= sm.dvec[c]; }
  __syncthreads();
  for (int e = tid; e < 64 * 65; e += 256) sm.Us[e] = 0.0f;
  __syncthreads();
  if (tid < 64) {
    int b = tid >> 5, c0 = tid & 31, base = b * 32, gc = base + c0;
    sm.Us[gc * 65 + gc] = 1.0f / sm.Ls[gc * 65 + gc];
    for (int r = c0 + 1; r < 32; ++r) {
      int gr = base + r;
      float acc = 0.0f;
      for (int l = c0; l < r; ++l) acc += sm.Ls[gr * 65 + base + l] * sm.Us[(base + l) * 65 + gc];
      sm.Us[gr * 65 + gc] = -acc / sm.Ls[gr * 65 + gr];
    }
  }
  __syncthreads();
  for (int e = tid; e < 1024; e += 256) {
    int r = e >> 5, c = e & 31;
    float acc = 0.0f;
    for (int l = c; l < 32; ++l) acc += sm.Ls[(32 + r) * 65 + l] * sm.Us[l * 65 + c];
    sm.Tt[r * 33 + c] = acc;
  }
  __syncthreads();
  for (int e = tid; e < 1024; e += 256) {
    int r = e >> 5, c = e & 31;
    float acc = 0.0f;
    for (int l = 0; l <= r; ++l) acc += sm.Us[(32 + r) * 65 + 32 + l] * sm.Tt[l * 33 + c];
    sm.Us[(32 + r) * 65 + c] = -acc;
  }
  __syncthreads();
  for (int e = tid; e < 4096; e += 256) { int r = e >> 6, c = e & 63; Uout[(size_t)r * ldu + c] = sm.Us[r * 65 + c]; }
}

// ---------------- phases ----------------

// build K lower tiles; tile (0,0) factored+inverted in-LDS immediately
__device__ void ph_buildK(SMem& sm, const float* xm, float* Km, float* Am,
                          float ls, float os, float noi, int n, int nb, int lb, int nbp) {
  int tid = threadIdx.x;
  float il2 = 1.0f / (ls * ls);
  int njobs = nb * (nb + 1) / 2;
  for (int job = lb; job < njobs; job += nbp) {
    int bi, bj; lt_decode(job, bi, bj);
    __syncthreads();
    if (tid < 64) {
      int r = bi * 64 + tid;
      sm.xi[tid][0] = xm[r * 3 + 0]; sm.xi[tid][1] = xm[r * 3 + 1]; sm.xi[tid][2] = xm[r * 3 + 2];
    } else if (tid < 128) {
      int lr = tid - 64; int r = bj * 64 + lr;
      sm.xj[lr][0] = xm[r * 3 + 0]; sm.xj[lr][1] = xm[r * 3 + 1]; sm.xj[lr][2] = xm[r * 3 + 2];
    }
    __syncthreads();
    if (job == 0) {
      for (int e = tid; e < 4096; e += 256) {
        int r = e >> 6, c = e & 63;
        float d0 = sm.xi[r][0] - sm.xj[c][0], d1 = sm.xi[r][1] - sm.xj[c][1], d2 = sm.xi[r][2] - sm.xj[c][2];
        float r2 = d0 * d0 + d1 * d1 + d2 * d2;
        float z = fmaxf(r2 * il2, 1e-12f);
        float dd = sqrtf(z);
        float kv = os * (1.0f + S5 * dd + (5.0f / 3.0f) * z) * expf(-S5 * dd);
        if (r == c) kv += noi;
        sm.Ls[r * 65 + c] = kv;
      }
      __syncthreads();
      factor64(sm, Am, n);
    } else {
      for (int e = tid; e < 4096; e += 256) {
        int r = e >> 6, c = e & 63;
        float d0 = sm.xi[r][0] - sm.xj[c][0], d1 = sm.xi[r][1] - sm.xj[c][1], d2 = sm.xi[r][2] - sm.xj[c][2];
        float r2 = d0 * d0 + d1 * d1 + d2 * d2;
        float z = fmaxf(r2 * il2, 1e-12f);
        float dd = sqrtf(z);
        float kv = os * (1.0f + S5 * dd + (5.0f / 3.0f) * z) * expf(-S5 * dd);
        if (bi == bj && r == c) kv += noi;
        Km[(size_t)(bi * 64 + r) * n + bj * 64 + c] = kv;
      }
    }
  }
}

// merged panel+trail (one phase per k): job (di,dj) recomputes P_i = K[i,k]*Linv^T
// (and P_j), applies K[i,j] -= P_i P_j^T. Diag jobs (di==dj) store P_i as the L
// panel into Ab[i,k]. Job 0 = (k+1,k+1): Schur-update in LDS + factor+invert.
__device__ void ph_trailM(SMem& sm, float* Km, float* Am, float* al,
                          int k, int n, int t, int lb, int nbp) {
  int tid = threadIdx.x, tx = tid & 15, ty = tid >> 4;
  if (k == 0) {  // zero alpha for this step (read last at prior buildK phase)
    int zi = lb * 256 + tid;
    if (zi < n) al[zi] = 0.0f;
  }
  const float* Linv = Am + (size_t)(k * 64) * n + k * 64;
  int njobs = t * (t + 1) / 2;
  for (int job = lb; job < njobs; job += nbp) {
    int di, dj; lt_decode(job, di, dj);
    int i = k + 1 + di, j = k + 1 + dj;
    float pp[4][4] = {};
    gemm64<0, 1>(Km + (size_t)(i * 64) * n + k * 64, n, Linv, n, 0, 64, pp, sm);
    __syncthreads();
#pragma unroll
    for (int ii = 0; ii < 4; ++ii)
#pragma unroll
      for (int jj = 0; jj < 4; ++jj) sm.Ls[(ty * 4 + ii) * 65 + tx * 4 + jj] = pp[ii][jj];
    if (di == dj) {
      float* P = Am + (size_t)(i * 64) * n + k * 64;  // store L panel tile (i,k)
#pragma unroll
      for (int ii = 0; ii < 4; ++ii)
#pragma unroll
        for (int jj = 0; jj < 4; ++jj) P[(size_t)(ty * 4 + ii) * n + tx * 4 + jj] = pp[ii][jj];
    } else {
#pragma unroll
      for (int ii = 0; ii < 4; ++ii)
#pragma unroll
        for (int jj = 0; jj < 4; ++jj) pp[ii][jj] = 0.0f;
      gemm64<0, 1>(Km + (size_t)(j * 64) * n + k * 64, n, Linv, n, 0, 64, pp, sm);
#pragma unroll
      for (int ii = 0; ii < 4; ++ii)
#pragma unroll
        for (int jj = 0; jj < 4; ++jj) sm.Us[(ty * 4 + ii) * 65 + tx * 4 + jj] = pp[ii][jj];
    }
    __syncthreads();
    float acc[4][4] = {};
    {
      const float* Bsrc = (di == dj) ? sm.Ls : sm.Us;
      for (int l = 0; l < 64; ++l) {
        float a[4], b[4];
#pragma unroll
        for (int ii = 0; ii < 4; ++ii) a[ii] = sm.Ls[(ty * 4 + ii) * 65 + l];
#pragma unroll
        for (int jj = 0; jj < 4; ++jj) b[jj] = Bsrc[(tx * 4 + jj) * 65 + l];
#pragma unroll
        for (int ii = 0; ii < 4; ++ii)
#pragma unroll
          for (int jj = 0; jj < 4; ++jj) acc[ii][jj] = fmaf(a[ii], b[jj], acc[ii][jj]);
      }
    }
    float* C = Km + (size_t)(i * 64) * n + j * 64;
    if (job == 0) {
      __syncthreads();
#pragma unroll
      for (int ii = 0; ii < 4; ++ii)
#pragma unroll
        for (int jj = 0; jj < 4; ++jj)
          sm.Ls[(ty * 4 + ii) * 65 + tx * 4 + jj] =
              C[(size_t)(ty * 4 + ii) * n + tx * 4 + jj] - acc[ii][jj];
      __syncthreads();
      factor64(sm, Am + (size_t)((k + 1) * 64) * n + (k + 1) * 64, n);
    } else {
#pragma unroll
      for (int ii = 0; ii < 4; ++ii)
#pragma unroll
        for (int jj = 0; jj < 4; ++jj)
          C[(size_t)(ty * 4 + ii) * n + tx * 4 + jj] -= acc[ii][jj];
    }
  }
}

// fused trinv level s=64: per pair p, T = L21*A11 then A21 = -A22*T, one block
__device__ void ph_trinv64(SMem& sm, float* Am, int n, int lb, int nbp) {
  int tid = threadIdx.x, tx = tid & 15, ty = tid >> 4;
  int np = n >> 7;
  for (int p = lb; p < np; p += nbp) {
    int rb = (2 * p + 1) * 64, cb = 2 * p * 64;
    __syncthreads();
    for (int e = tid; e < 4096; e += 256) {
      int r = e >> 6, c = e & 63;
      sm.Ls[r * 65 + c] = Am[(size_t)(rb + r) * n + cb + c];  // L21
      sm.Us[r * 65 + c] = Am[(size_t)(cb + r) * n + cb + c];  // A11 (upper=0)
    }
    __syncthreads();
    float tt[4][4] = {};
    for (int l = 0; l < 64; ++l) {
      float a[4], b[4];
#pragma unroll
      for (int ii = 0; ii < 4; ++ii) a[ii] = sm.Ls[(ty * 4 + ii) * 65 + l];
#pragma unroll
      for (int jj = 0; jj < 4; ++jj) b[jj] = sm.Us[l * 65 + tx * 4 + jj];
#pragma unroll
      for (int ii = 0; ii < 4; ++ii)
#pragma unroll
        for (int jj = 0; jj < 4; ++jj) tt[ii][jj] = fmaf(a[ii], b[jj], tt[ii][jj]);
    }
    __syncthreads();
#pragma unroll
    for (int ii = 0; ii < 4; ++ii)
#pragma unroll
      for (int jj = 0; jj < 4; ++jj) sm.Ls[(ty * 4 + ii) * 65 + tx * 4 + jj] = tt[ii][jj];
    for (int e = tid; e < 4096; e += 256) {
      int r = e >> 6, c = e & 63;
      sm.Us[r * 65 + c] = Am[(size_t)(rb + r) * n + rb + c];  // A22 (upper=0)
    }
    __syncthreads();
    float oo[4][4] = {};
    for (int l = 0; l < 64; ++l) {
      float a[4], b[4];
#pragma unroll
      for (int ii = 0; ii < 4; ++ii) a[ii] = sm.Us[(ty * 4 + ii) * 65 + l];
#pragma unroll
      for (int jj = 0; jj < 4; ++jj) b[jj] = sm.Ls[l * 65 + tx * 4 + jj];
#pragma unroll
      for (int ii = 0; ii < 4; ++ii)
#pragma unroll
        for (int jj = 0; jj < 4; ++jj) oo[ii][jj] = fmaf(a[ii], b[jj], oo[ii][jj]);
    }
#pragma unroll
    for (int ii = 0; ii < 4; ++ii)
#pragma unroll
      for (int jj = 0; jj < 4; ++jj)
        Am[(size_t)(rb + ty * 4 + ii) * n + cb + tx * 4 + jj] = -oo[ii][jj];
  }
}

// trinv T = L21 * A11 (L21 panels now live in Ab)
__device__ void ph_trinvT(SMem& sm, const float* Am, float* Tm, int s, int n, int lb, int nbp) {
  int tx = threadIdx.x & 15, ty = threadIdx.x >> 4;
  int st = s >> 6, np = n / (2 * s);
  int njobs = np * st * st;
  for (int job = lb; job < njobs; job += nbp) {
    int p = job / (st * st), rem = job % (st * st);
    int ti = rem / st, tj = rem % st;
    int base = p * 2 * s;
    float acc[4][4] = {};
    gemm64<0, 0>(Am + (size_t)(base + s + ti * 64) * n + base, n,
                 Am + (size_t)base * n + base + tj * 64, n, tj * 64, s, acc, sm);
    float* C = Tm + (size_t)p * s * s + (size_t)(ti * 64) * s + tj * 64;
#pragma unroll
    for (int ii = 0; ii < 4; ++ii)
#pragma unroll
      for (int jj = 0; jj < 4; ++jj) C[(size_t)(ty * 4 + ii) * s + tx * 4 + jj] = acc[ii][jj];
  }
}

__device__ void ph_trinvA(SMem& sm, float* Am, const float* Tm, int s, int n, int lb, int nbp) {
  int tx = threadIdx.x & 15, ty = threadIdx.x >> 4;
  int st = s >> 6, np = n / (2 * s);
  int njobs = np * st * st;
  for (int job = lb; job < njobs; job += nbp) {
    int p = job / (st * st), rem = job % (st * st);
    int ti = rem / st, tj = rem % st;
    int base = p * 2 * s;
    float acc[4][4] = {};
    gemm64<0, 0>(Am + (size_t)(base + s + ti * 64) * n + base + s, n,
                 Tm + (size_t)p * s * s + tj * 64, s, 0, (ti + 1) * 64, acc, sm);
    float* C = Am + (size_t)(base + s + ti * 64) * n + base + tj * 64;
#pragma unroll
    for (int ii = 0; ii < 4; ++ii)
#pragma unroll
      for (int jj = 0; jj < 4; ++jj) C[(size_t)(ty * 4 + ii) * n + tx * 4 + jj] = -acc[ii][jj];
  }
}

// syrk + fused alpha + fused tr(G)
__device__ void ph_syrkAT(SMem& sm, const float* Am, float* Gm, const float* ym,
                          float* accp, float* al, float cm, int n, int nb, int lb, int nbp) {
  int tid = threadIdx.x, tx = tid & 15, ty = tid >> 4;
  int njobs = nb * (nb + 1) / 2;
  for (int job = lb; job < njobs; job += nbp) {
    int ib, jb; lt_decode(job, ib, jb);
    __syncthreads();
    if (tid < 64) sm.ai[tid] = ym[ib * 64 + tid] - cm;
    else if (tid < 128) sm.aj[tid - 64] = ym[jb * 64 + tid - 64] - cm;
    float acc[4][4] = {};
    gemm64<1, 0>(Am + ib * 64, n, Am + jb * 64, n, ib * 64, n, acc, sm);
#pragma unroll
    for (int ii = 0; ii < 4; ++ii)
#pragma unroll
      for (int jj = 0; jj < 4; ++jj) {
        int r = ty * 4 + ii, c = tx * 4 + jj;
        Gm[(size_t)(ib * 64 + r) * n + jb * 64 + c] = acc[ii][jj];
        if (ib != jb) Gm[(size_t)(jb * 64 + c) * n + ib * 64 + r] = acc[ii][jj];
      }
    if (ib == jb && tx == ty) {
      atomicAdd(&accp[2], acc[0][0] + acc[1][1] + acc[2][2] + acc[3][3]);
    }
    float rowp[4];
#pragma unroll
    for (int i = 0; i < 4; ++i) {
      float s = 0.0f;
#pragma unroll
      for (int j = 0; j < 4; ++j) s = fmaf(acc[i][j], sm.aj[tx * 4 + j], s);
      rowp[i] = s;
    }
    float colp[4];
    if (ib != jb) {
#pragma unroll
      for (int j = 0; j < 4; ++j) {
        float s = 0.0f;
#pragma unroll
        for (int i = 0; i < 4; ++i) s = fmaf(acc[i][j], sm.ai[ty * 4 + i], s);
        colp[j] = s;
      }
    }
    __syncthreads();
    float* redA = &sm.As[0][0];
    float* redB = &sm.Bs[0][0];
#pragma unroll
    for (int i = 0; i < 4; ++i) redA[(ty * 4 + i) * 16 + tx] = rowp[i];
    if (ib != jb) {
#pragma unroll
      for (int j = 0; j < 4; ++j) redB[(tx * 4 + j) * 16 + ty] = colp[j];
    }
    __syncthreads();
    if (tid < 64) {
      float s = 0.0f;
#pragma unroll
      for (int q = 0; q < 16; ++q) s += redA[tid * 16 + q];
      atomicAdd(&al[ib * 64 + tid], s);
      if (ib != jb) {
        float s2 = 0.0f;
#pragma unroll
        for (int q = 0; q < 16; ++q) s2 += redB[tid * 16 + q];
        atomicAdd(&al[jb * 64 + tid], s2);
      }
    }
  }
}

// reduce: T1 = <G,C>, T2 = alpha^T C alpha (lower-tri, weight 2 off-diag)
__device__ void ph_reduce(SMem& sm, const float* Gm, const float* xm, const float* al,
                          float* accp, float ls, float os, int n, int nb, int lb, int nbp) {
  int tid = threadIdx.x;
  int njobs = nb * (nb + 1) / 2;
  float il2 = 1.0f / (ls * ls);
  float c53 = (5.0f / 3.0f) * os / ls;
  for (int job = lb; job < njobs; job += nbp) {
    int bi, bj; lt_decode(job, bi, bj);
    float w = (bi == bj) ? 1.0f : 2.0f;
    __syncthreads();
    if (tid < 64) {
      int r = bi * 64 + tid;
      sm.xi[tid][0] = xm[r * 3 + 0]; sm.xi[tid][1] = xm[r * 3 + 1]; sm.xi[tid][2] = xm[r * 3 + 2];
      sm.ai[tid] = al[r];
    } else if (tid < 128) {
      int lr = tid - 64; int r = bj * 64 + lr;
      sm.xj[lr][0] = xm[r * 3 + 0]; sm.xj[lr][1] = xm[r * 3 + 1]; sm.xj[lr][2] = xm[r * 3 + 2];
      sm.aj[lr] = al[r];
    }
    __syncthreads();
    float a1 = 0.0f, a2 = 0.0f;
    for (int e = tid; e < 4096; e += 256) {
      int r = e >> 6, c = e & 63;
      float d0 = sm.xi[r][0] - sm.xj[c][0], d1 = sm.xi[r][1] - sm.xj[c][1], d2 = sm.xi[r][2] - sm.xj[c][2];
      float r2 = d0 * d0 + d1 * d1 + d2 * d2;
      float z = fmaxf(r2 * il2, 1e-12f);
      float dd = sqrtf(z);
      float Cv = c53 * z * (1.0f + S5 * dd) * expf(-S5 * dd);
      float g = Gm[(size_t)(bi * 64 + r) * n + bj * 64 + c];
      a1 = fmaf(g, Cv, a1);
      a2 = fmaf(sm.ai[r] * sm.aj[c], Cv, a2);
    }
    a1 *= w; a2 *= w;
    for (int off = 32; off; off >>= 1) { a1 += __shfl_down(a1, off); a2 += __shfl_down(a2, off); }
    int wid = tid >> 6, lane = tid & 63;
    if (lane == 0) { sm.red[wid][0] = a1; sm.red[wid][1] = a2; }
    __syncthreads();
    if (tid == 0) {
      a1 = sm.red[0][0] + sm.red[1][0] + sm.red[2][0] + sm.red[3][0];
      a2 = sm.red[0][1] + sm.red[1][1] + sm.red[2][1] + sm.red[3][1];
      atomicAdd(&accp[0], a1);
      atomicAdd(&accp[1], a2);
    }
  }
}

// prediction
__device__ void ph_buildKtc(SMem& sm, const float* xtm, const float* xm, float* Kt,
                            float ls, float os, float* S1, float* S2, int lb, int nbp) {
  int tid = threadIdx.x;
  {
    int z = lb * 256 + tid;
    if (z < NT) { S1[z] = 0.0f; S2[z] = 0.0f; }
  }
  float il2 = 1.0f / (ls * ls);
  int njobs = (NT / 64) * (NC / 64);
  for (int job = lb; job < njobs; job += nbp) {
    int ti = job >> 4, tj = job & 15;
    __syncthreads();
    if (tid < 64) {
      int r = ti * 64 + tid;
      sm.xi[tid][0] = xtm[r * 3 + 0]; sm.xi[tid][1] = xtm[r * 3 + 1]; sm.xi[tid][2] = xtm[r * 3 + 2];
    } else if (tid < 128) {
      int lr = tid - 64; int r = tj * 64 + lr;
      sm.xj[lr][0] = xm[r * 3 + 0]; sm.xj[lr][1] = xm[r * 3 + 1]; sm.xj[lr][2] = xm[r * 3 + 2];
    }
    __syncthreads();
    for (int e = tid; e < 4096; e += 256) {
      int r = e >> 6, c = e & 63;
      float d0 = sm.xi[r][0] - sm.xj[c][0], d1 = sm.xi[r][1] - sm.xj[c][1], d2 = sm.xi[r][2] - sm.xj[c][2];
      float r2 = d0 * d0 + d1 * d1 + d2 * d2;
      float z = fmaxf(r2 * il2, 1e-12f);
      float dd = sqrtf(z);
      float kv = os * (1.0f + S5 * dd + (5.0f / 3.0f) * z) * expf(-S5 * dd);
      Kt[(size_t)(ti * 64 + r) * NC + tj * 64 + c] = kv;
    }
  }
}

__device__ void ph_predW(SMem& sm, const float* Kt, const float* Gm, const float* al,
                         float* S1, float* S2, int lb, int nbp) {
  int tid = threadIdx.x, tx = tid & 15, ty = tid >> 4;
  int njobs = (NT / 64) * (NC / 64);
  for (int job = lb; job < njobs; job += nbp) {
    int ti = job >> 4, tj = job & 15;
    __syncthreads();
    if (tid < 64) sm.aj[tid] = al[tj * 64 + tid];
    float acc[4][4] = {};
    gemm64<0, 0>(Kt + (size_t)(ti * 64) * NC, NC, Gm + tj * 64, 1024, 0, 1024, acc, sm);
    float s1p[4], s2p[4];
#pragma unroll
    for (int i = 0; i < 4; ++i) {
      float a1 = 0.0f, a2 = 0.0f;
      const float* kr = Kt + (size_t)(ti * 64 + ty * 4 + i) * NC + tj * 64;
#pragma unroll
      for (int j = 0; j < 4; ++j) {
        float kv = kr[tx * 4 + j];
        a1 = fmaf(kv, sm.aj[tx * 4 + j], a1);
        a2 = fmaf(kv, acc[i][j], a2);
      }
      s1p[i] = a1; s2p[i] = a2;
    }
    __syncthreads();
    float* redA = &sm.As[0][0];
    float* redB = &sm.Bs[0][0];
#pragma unroll
    for (int i = 0; i < 4; ++i) {
      redA[(ty * 4 + i) * 16 + tx] = s1p[i];
      redB[(ty * 4 + i) * 16 + tx] = s2p[i];
    }
    __syncthreads();
    if (tid < 64) {
      float a1 = 0.0f, a2 = 0.0f;
#pragma unroll
      for (int q = 0; q < 16; ++q) { a1 += redA[tid * 16 + q]; a2 += redB[tid * 16 + q]; }
      atomicAdd(&S1[ti * 64 + tid], a1);
      atomicAdd(&S2[ti * 64 + tid], a2);
    }
  }
}

// ---------------- mega kernel ------------------------------------------------
__global__ void __launch_bounds__(256, 3)
mega(const float* xc, const float* yc, const float* xt, float* out, float* ws, int nbp) {
  __shared__ SMem sm;
  int pm = blockIdx.x & 7;   // XCD-pinned partition (round-robin dispatch heuristic)
  int lb = blockIdx.x >> 3;
  float* Km = ws + (size_t)pm * 1048576;
  float* Am = ws + OFF_A + (size_t)pm * 1048576;
  float* Tm = ws + OFF_T + (size_t)pm * 262144;
  float* Kt = ws + OFF_KTC + (size_t)pm * NT * NC;
  float* al = ws + OFF_ALPHA + (size_t)pm * 1024;
  float* accA = ws + OFF_ACC + (size_t)pm * 8;
  unsigned* barm = (unsigned*)(ws + OFF_BAR) + (size_t)pm * 128;
  const float* xm = xc + (size_t)pm * NC * 3;
  const float* ym = yc + (size_t)pm * NC;
  const float* xtm = xt + (size_t)pm * NT * 3;
  float* S1 = Tm;
  float* S2 = Tm + NT;
  unsigned per = (unsigned)(nbp >> 2);
  int tid = threadIdx.x;

  // hyperparams + Adam state in registers — identical in every thread/block
  float raw0 = 0, raw1 = 0, raw2 = 0, raw3 = 0;
  float am0 = 0, am1 = 0, am2 = 0, am3 = 0, av0 = 0, av1 = 0, av2 = 0, av3 = 0;
  float ls = 0.69314718056f, os = 0.69314718056f, noi = 0.69314718056f + 1e-4f, cm = 0.0f;

  int epoch = 0;
  for (int step = 0; step < 17; ++step) {
    int n = step < 8 ? 512 : 1024;
    int nb = n >> 6;

    if (step > 0) {
      // local Adam: every block computes the identical update (no barrier/phase)
      int pn = step <= 8 ? 512 : 1024;
      int pp = (step - 1) & 1;
      float t4 = 0, t5 = 0, t6 = 0;
      for (int i2 = tid; i2 < pn; i2 += 256) {
        float a = al[i2];
        t4 = fmaf(a, a, t4); t5 += a; t6 = fmaf(ym[i2] - cm, a, t6);
      }
      for (int off = 32; off; off >>= 1) {
        t4 += __shfl_down(t4, off); t5 += __shfl_down(t5, off); t6 += __shfl_down(t6, off);
      }
      int wid = tid >> 6, lane = tid & 63;
      if (lane == 0) { sm.red[wid][0] = t4; sm.red[wid][1] = t5; sm.red[wid][2] = t6; }
      __syncthreads();
      t4 = sm.red[0][0] + sm.red[1][0] + sm.red[2][0] + sm.red[3][0];
      t5 = sm.red[0][1] + sm.red[1][1] + sm.red[2][1] + sm.red[3][1];
      t6 = sm.red[0][2] + sm.red[1][2] + sm.red[2][2] + sm.red[3][2];
      float T1 = accA[pp * 4], T2 = accA[pp * 4 + 1], t3 = accA[pp * 4 + 2];
      float fn = (float)pn;
      float g_ls = 0.5f / fn * (T1 - T2);
      float g_os = 0.5f / (fn * os) * (fn - noi * t3 - t6 + noi * t4);
      float g_no = 0.5f / fn * (t3 - t4);
      float g_c = -t5 / fn;
      float gr0 = g_ls * sigmf(raw0), gr1 = g_os * sigmf(raw1);
      float gr2 = g_no * sigmf(raw2), gr3 = g_c;
      float bc1 = 1.0f - powf(0.9f, (float)step);
      float bc2 = 1.0f - powf(0.999f, (float)step);
      am0 = 0.9f * am0 + 0.1f * gr0; av0 = 0.999f * av0 + 0.001f * gr0 * gr0;
      raw0 -= 0.1f * (am0 / bc1) / (sqrtf(av0 / bc2) + 1e-8f);
      am1 = 0.9f * am1 + 0.1f * gr1; av1 = 0.999f * av1 + 0.001f * gr1 * gr1;
      raw1 -= 0.1f * (am1 / bc1) / (sqrtf(av1 / bc2) + 1e-8f);
      am2 = 0.9f * am2 + 0.1f * gr2; av2 = 0.999f * av2 + 0.001f * gr2 * gr2;
      raw2 -= 0.1f * (am2 / bc1) / (sqrtf(av2 / bc2) + 1e-8f);
      am3 = 0.9f * am3 + 0.1f * gr3; av3 = 0.999f * av3 + 0.001f * gr3 * gr3;
      raw3 -= 0.1f * (am3 / bc1) / (sqrtf(av3 / bc2) + 1e-8f);
      ls = softplusf(raw0); os = softplusf(raw1); noi = softplusf(raw2) + 1e-4f; cm = raw3;
      __syncthreads();
    }
    if (lb == 0 && tid < 4) accA[(step & 1) * 4 + tid] = 0.0f;  // zero THIS step's set

    ph_buildK(sm, xm, Km, Am, ls, os, noi, n, nb, lb, nbp);
    gbar(barm, lb, per, epoch);

    for (int k = 0; k <= nb - 2; ++k) {
      ph_trailM(sm, Km, Am, al, k, n, nb - 1 - k, lb, nbp);
      gbar(barm, lb, per, epoch);
    }
    ph_trinv64(sm, Am, n, lb, nbp);
    gbar(barm, lb, per, epoch);
    for (int s2 = 128; s2 < n; s2 <<= 1) {
      ph_trinvT(sm, Am, Tm, s2, n, lb, nbp);
      gbar(barm, lb, per, epoch);
      ph_trinvA(sm, Am, Tm, s2, n, lb, nbp);
      gbar(barm, lb, per, epoch);
    }
    ph_syrkAT(sm, Am, Km, ym, accA + (step & 1) * 4, al, cm, n, nb, lb, nbp);
    gbar(barm, lb, per, epoch);
    if (step < 16) {
      ph_reduce(sm, Km, xm, al, accA + (step & 1) * 4, ls, os, n, nb, lb, nbp);
      gbar(barm, lb, per, epoch);
    }
  }

  ph_buildKtc(sm, xtm, xm, Kt, ls, os, S1, S2, lb, nbp);
  gbar(barm, lb, per, epoch);
  ph_predW(sm, Kt, Km, al, S1, S2, lb, nbp);
  gbar(barm, lb, per, epoch);
  {
    int t = lb * 256 + tid;
    if (t < NT) {
      out[(size_t)pm * NT + t] = cm + S1[t];
      out[(size_t)MM * NT + (size_t)pm * NT + t] = os + noi - S2[t];
    }
  }
}

// ---------------- init ----------------
__global__ void k_init(float* accA, unsigned* bar) {
  int t = threadIdx.x;
  for (int i = t; i < MM * 8; i += 256) accA[i] = 0.0f;
  for (int i = t; i < MM * 128; i += 256) bar[i] = 0u;
}

// ---------------- host ----------------
extern "C" void kernel_launch(void* const* d_in, const int* in_sizes, int n_in,
                              void* d_out, int out_size, void* d_ws, size_t ws_size,
                              hipStream_t stream) {
  const float* xc = (const float*)d_in[0];
  const float* yc = (const float*)d_in[1];
  const float* xt = (const float*)d_in[2];
  float* out = (float*)d_out;
  float* ws = (float*)d_ws;
  float* accA = ws + OFF_ACC;
  unsigned* bar = (unsigned*)(ws + OFF_BAR);

  k_init<<<dim3(1), dim3(256), 0, stream>>>(accA, bar);

  int maxb = 0;
  hipError_t qe = hipOccupancyMaxActiveBlocksPerMultiprocessor(&maxb, mega, 256, 0);
  if (qe != hipSuccess || maxb < 2) maxb = 2;
  if (maxb > 3) maxb = 3;
  int nbp = 32 * maxb;        // blocks per partition (multiple of 4)
  int grid = 8 * nbp;

  void* args[6];
  args[0] = (void*)&xc; args[1] = (void*)&yc; args[2] = (void*)&xt;
  args[3] = (void*)&out; args[4] = (void*)&ws; args[5] = (void*)&nbp;
  hipError_t le = hipLaunchCooperativeKernel(mega, dim3(grid), dim3(256), args, 0u, stream);
  if (le != hipSuccess) {
    (void)hipGetLastError();
    mega<<<dim3(grid), dim3(256), 0, stream>>>(xc, yc, xt, out, ws, nbp);
  }

  (void)in_sizes; (void)n_in; (void)out_size; (void)ws_size;
}

// Round 6
// 19787.389 us; speedup vs baseline: 1.6044x; 1.6044x over previous
//
#include <hip/hip_runtime.h>
#include <math.h>

// ---------------- problem constants ----------------
constexpr int MM = 8;      // batch of GPs
constexpr int NC = 1024;   // context points
constexpr int NT = 512;    // target points

// Workspace (floats):
//  Kb   : MM*1024*1024   (K raw/Schur -> G = K^-1 after syrk)
//  Ab   : MM*1024*1024   (diag-block inverses + L panels -> A = L^-1)
//  Tb   : MM*512*512     (trinv temp; S1/S2 at predict)
//  Ktc  : MM*NT*NC
//  alpha: MM*1024
//  scal : MM*32  ([0..3] raw, [4..7] adam m, [8..11] adam v, [12]ls [13]os [14]noi [15]cm)
//  acc  : MM*8   ([T1, T2, trG] per m)
constexpr size_t OFF_A     = (size_t)MM * 1024 * 1024;
constexpr size_t OFF_T     = OFF_A * 2;
constexpr size_t OFF_KTC   = OFF_T + (size_t)MM * 512 * 512;
constexpr size_t OFF_ALPHA = OFF_KTC + (size_t)MM * NT * NC;
constexpr size_t OFF_SCAL  = OFF_ALPHA + (size_t)MM * 1024;
constexpr size_t OFF_ACC   = OFF_SCAL + (size_t)MM * 32;

#define S5 2.2360679775f

__device__ __forceinline__ float sigmf(float x) { return 1.0f / (1.0f + expf(-x)); }
__device__ __forceinline__ float softplusf(float x) { return fmaxf(x, 0.0f) + log1pf(expf(-fabsf(x))); }

__device__ __forceinline__ void lt_decode(int x, int& i, int& j) {
  int ii = 0;
  while ((ii + 1) * (ii + 2) / 2 <= x) ++ii;
  i = ii; j = x - ii * (ii + 1) / 2;
}

// Shared-memory struct (~47.5 KB)
struct SMem {
  float Ls[64 * 65];
  float Us[64 * 65];
  float Tt[32 * 33];
  float dvec[64];
  float As[16][68];
  float Bs[16][68];
  float xi[64][3];
  float xj[64][3];
  float ai[64];
  float aj[64];
  float red[4][4];
};

// ---------------- 64x64-tile GEMM, register-prefetch double-buffered ---------
template <int TA, int TB>
__device__ __forceinline__ void gemm64(const float* __restrict__ A, int lda,
                                       const float* __restrict__ B, int ldb,
                                       int kBeg, int kEnd, float acc[4][4], SMem& sm) {
  int tid = threadIdx.x, tx = tid & 15, ty = tid >> 4;
  float ra[4], rb[4];
  auto ldAB = [&](int k0) {
#pragma unroll
    for (int q = 0; q < 4; ++q) {
      int e = tid + (q << 8);
      if (TA) { int kk = e >> 6, r = e & 63; ra[q] = A[(size_t)(k0 + kk) * lda + r]; }
      else    { int r = e >> 4, kk = e & 15; ra[q] = A[(size_t)r * lda + k0 + kk]; }
      if (TB) { int c = e >> 4, kk = e & 15; rb[q] = B[(size_t)c * ldb + k0 + kk]; }
      else    { int kk = e >> 6, c = e & 63; rb[q] = B[(size_t)(k0 + kk) * ldb + c]; }
    }
  };
  ldAB(kBeg);
  for (int k0 = kBeg; k0 < kEnd; k0 += 16) {
    __syncthreads();
#pragma unroll
    for (int q = 0; q < 4; ++q) {
      int e = tid + (q << 8);
      if (TA) sm.As[e >> 6][e & 63] = ra[q]; else sm.As[e & 15][e >> 4] = ra[q];
      if (TB) sm.Bs[e & 15][e >> 4] = rb[q]; else sm.Bs[e >> 6][e & 63] = rb[q];
    }
    __syncthreads();
    if (k0 + 16 < kEnd) ldAB(k0 + 16);
#pragma unroll
    for (int kk = 0; kk < 16; ++kk) {
      float a[4], b[4];
#pragma unroll
      for (int i = 0; i < 4; ++i) a[i] = sm.As[kk][ty * 4 + i];
#pragma unroll
      for (int j = 0; j < 4; ++j) b[j] = sm.Bs[kk][tx * 4 + j];
#pragma unroll
      for (int i = 0; i < 4; ++i)
#pragma unroll
        for (int j = 0; j < 4; ++j) acc[i][j] = fmaf(a[i], b[j], acc[i][j]);
    }
  }
}

// ---------------- in-LDS 64x64 SPD factor + triangular inverse ---------------
__device__ void factor64(SMem& sm, float* Uout, int ldu) {
  int tid = threadIdx.x;
  int tx = tid & 15, ty = tid >> 4;
  for (int j = 0; j < 63; ++j) {
    float rinv = 1.0f / sm.Ls[j * 65 + j];
    for (int i = j + 1 + ty; i < 64; i += 16) {
      float lij = sm.Ls[i * 65 + j] * rinv;
      for (int c = j + 1 + tx; c <= i; c += 16) sm.Ls[i * 65 + c] -= lij * sm.Ls[c * 65 + j];
    }
    __syncthreads();
  }
  if (tid < 64) sm.dvec[tid] = 1.0f / sqrtf(sm.Ls[tid * 65 + tid]);
  __syncthreads();
  for (int e = tid; e < 4096; e += 256) { int r = e >> 6, c = e & 63; if (c <= r) sm.Ls[r * 65 + c] *= sm.dvec[c]; }
  __syncthreads();
  for (int e = tid; e < 64 * 65; e += 256) sm.Us[e] = 0.0f;
  __syncthreads();
  if (tid < 64) {
    int b = tid >> 5, c0 = tid & 31, base = b * 32, gc = base + c0;
    sm.Us[gc * 65 + gc] = 1.0f / sm.Ls[gc * 65 + gc];
    for (int r = c0 + 1; r < 32; ++r) {
      int gr = base + r;
      float acc = 0.0f;
      for (int l = c0; l < r; ++l) acc += sm.Ls[gr * 65 + base + l] * sm.Us[(base + l) * 65 + gc];
      sm.Us[gr * 65 + gc] = -acc / sm.Ls[gr * 65 + gr];
    }
  }
  __syncthreads();
  for (int e = tid; e < 1024; e += 256) {
    int r = e >> 5, c = e & 31;
    float acc = 0.0f;
    for (int l = c; l < 32; ++l) acc += sm.Ls[(32 + r) * 65 + l] * sm.Us[l * 65 + c];
    sm.Tt[r * 33 + c] = acc;
  }
  __syncthreads();
  for (int e = tid; e < 1024; e += 256) {
    int r = e >> 5, c = e & 31;
    float acc = 0.0f;
    for (int l = 0; l <= r; ++l) acc += sm.Us[(32 + r) * 65 + 32 + l] * sm.Tt[l * 33 + c];
    sm.Us[(32 + r) * 65 + c] = -acc;
  }
  __syncthreads();
  for (int e = tid; e < 4096; e += 256) { int r = e >> 6, c = e & 63; Uout[(size_t)r * ldu + c] = sm.Us[r * 65 + c]; }
}

// ---------------- discrete kernels (job = blockIdx.x, m = blockIdx.y) --------

__global__ __launch_bounds__(256) void k_init(float* ws) {
  int t = threadIdx.x;
  float* scal = ws + OFF_SCAL;
  float* acc = ws + OFF_ACC;
  if (t < MM) {
    float* s = scal + t * 32;
    for (int i = 0; i < 12; ++i) s[i] = 0.0f;
    float sp0 = 0.69314718056f;
    s[12] = sp0; s[13] = sp0; s[14] = sp0 + 1e-4f; s[15] = 0.0f;
  }
  if (t < MM * 8) acc[t] = 0.0f;
}

// adam: reads acc (T1,T2,trG) + alpha + y, updates params in scal. 8 blocks.
__global__ __launch_bounds__(256) void k_adam(const float* __restrict__ yc, float* ws,
                                              int pn, int tstep) {
  int m = blockIdx.x, tid = threadIdx.x;
  float* sT = ws + OFF_SCAL + m * 32;
  float* accp = ws + OFF_ACC + m * 8;
  const float* al = ws + OFF_ALPHA + (size_t)m * 1024;
  const float* ym = yc + (size_t)m * NC;
  __shared__ float red[4][4];
  float cm = sT[15];
  float t4 = 0, t5 = 0, t6 = 0;
  for (int i = tid; i < pn; i += 256) {
    float a = al[i];
    t4 = fmaf(a, a, t4); t5 += a; t6 = fmaf(ym[i] - cm, a, t6);
  }
  for (int off = 32; off; off >>= 1) {
    t4 += __shfl_down(t4, off); t5 += __shfl_down(t5, off); t6 += __shfl_down(t6, off);
  }
  int wid = tid >> 6, lane = tid & 63;
  if (lane == 0) { red[wid][0] = t4; red[wid][1] = t5; red[wid][2] = t6; }
  __syncthreads();
  if (tid == 0) {
    t4 = red[0][0] + red[1][0] + red[2][0] + red[3][0];
    t5 = red[0][1] + red[1][1] + red[2][1] + red[3][1];
    t6 = red[0][2] + red[1][2] + red[2][2] + red[3][2];
    float T1 = accp[0], T2 = accp[1], t3 = accp[2];
    float ls = sT[12], os = sT[13], noi = sT[14];
    float fn = (float)pn;
    float g_ls = 0.5f / fn * (T1 - T2);
    float g_os = 0.5f / (fn * os) * (fn - noi * t3 - t6 + noi * t4);
    float g_no = 0.5f / fn * (t3 - t4);
    float g_c = -t5 / fn;
    float gr[4];
    gr[0] = g_ls * sigmf(sT[0]);
    gr[1] = g_os * sigmf(sT[1]);
    gr[2] = g_no * sigmf(sT[2]);
    gr[3] = g_c;
    float bc1 = 1.0f - powf(0.9f, (float)tstep);
    float bc2 = 1.0f - powf(0.999f, (float)tstep);
#pragma unroll
    for (int i = 0; i < 4; ++i) {
      float mv = 0.9f * sT[4 + i] + 0.1f * gr[i];
      float vv = 0.999f * sT[8 + i] + 0.001f * gr[i] * gr[i];
      sT[4 + i] = mv; sT[8 + i] = vv;
      sT[i] = sT[i] - 0.1f * (mv / bc1) / (sqrtf(vv / bc2) + 1e-8f);
    }
    sT[12] = softplusf(sT[0]);
    sT[13] = softplusf(sT[1]);
    sT[14] = softplusf(sT[2]) + 1e-4f;
    sT[15] = sT[3];
  }
}

// build K lower tiles; job 0: build tile(0,0) in LDS + factor+invert ->Am.
// side tasks: jobs 1..4 zero alpha, job 5 zeroes acc.
__global__ __launch_bounds__(256) void k_buildK(const float* __restrict__ xc, float* ws, int n) {
  __shared__ SMem sm;
  int job = blockIdx.x, m = blockIdx.y, tid = threadIdx.x;
  const float* xm = xc + (size_t)m * NC * 3;
  float* Km = ws + (size_t)m * 1048576;
  float* Am = ws + OFF_A + (size_t)m * 1048576;
  const float* sT = ws + OFF_SCAL + m * 32;
  float ls = sT[12], os = sT[13], noi = sT[14];
  float il2 = 1.0f / (ls * ls);
  if (job >= 1 && job <= 4) {
    int zi = (job - 1) * 256 + tid;
    if (zi < n) ws[OFF_ALPHA + (size_t)m * 1024 + zi] = 0.0f;
  }
  if (job == 5 && tid < 4) ws[OFF_ACC + m * 8 + tid] = 0.0f;
  int bi, bj; lt_decode(job, bi, bj);
  if (tid < 64) {
    int r = bi * 64 + tid;
    sm.xi[tid][0] = xm[r * 3 + 0]; sm.xi[tid][1] = xm[r * 3 + 1]; sm.xi[tid][2] = xm[r * 3 + 2];
  } else if (tid < 128) {
    int lr = tid - 64; int r = bj * 64 + lr;
    sm.xj[lr][0] = xm[r * 3 + 0]; sm.xj[lr][1] = xm[r * 3 + 1]; sm.xj[lr][2] = xm[r * 3 + 2];
  }
  __syncthreads();
  if (job == 0) {
    for (int e = tid; e < 4096; e += 256) {
      int r = e >> 6, c = e & 63;
      float d0 = sm.xi[r][0] - sm.xj[c][0], d1 = sm.xi[r][1] - sm.xj[c][1], d2 = sm.xi[r][2] - sm.xj[c][2];
      float r2 = d0 * d0 + d1 * d1 + d2 * d2;
      float z = fmaxf(r2 * il2, 1e-12f);
      float dd = sqrtf(z);
      float kv = os * (1.0f + S5 * dd + (5.0f / 3.0f) * z) * expf(-S5 * dd);
      if (r == c) kv += noi;
      sm.Ls[r * 65 + c] = kv;
    }
    __syncthreads();
    factor64(sm, Am, n);
  } else {
    for (int e = tid; e < 4096; e += 256) {
      int r = e >> 6, c = e & 63;
      float d0 = sm.xi[r][0] - sm.xj[c][0], d1 = sm.xi[r][1] - sm.xj[c][1], d2 = sm.xi[r][2] - sm.xj[c][2];
      float r2 = d0 * d0 + d1 * d1 + d2 * d2;
      float z = fmaxf(r2 * il2, 1e-12f);
      float dd = sqrtf(z);
      float kv = os * (1.0f + S5 * dd + (5.0f / 3.0f) * z) * expf(-S5 * dd);
      if (bi == bj && r == c) kv += noi;
      Km[(size_t)(bi * 64 + r) * n + bj * 64 + c] = kv;
    }
  }
}

// merged panel+trail: job (di,dj) recomputes P_i=K[i,k]*Linv^T (and P_j),
// K[i,j] -= P_i P_j^T. di==dj stores P_i panel into Ab. job 0: LDS Schur +
// factor+invert of tile (k+1,k+1).
__global__ __launch_bounds__(256) void k_trail(float* ws, int k, int n) {
  __shared__ SMem sm;
  int job = blockIdx.x, m = blockIdx.y, tid = threadIdx.x;
  int tx = tid & 15, ty = tid >> 4;
  float* Km = ws + (size_t)m * 1048576;
  float* Am = ws + OFF_A + (size_t)m * 1048576;
  const float* Linv = Am + (size_t)(k * 64) * n + k * 64;
  int di, dj; lt_decode(job, di, dj);
  int i = k + 1 + di, j = k + 1 + dj;
  float pp[4][4] = {};
  gemm64<0, 1>(Km + (size_t)(i * 64) * n + k * 64, n, Linv, n, 0, 64, pp, sm);
  __syncthreads();
#pragma unroll
  for (int ii = 0; ii < 4; ++ii)
#pragma unroll
    for (int jj = 0; jj < 4; ++jj) sm.Ls[(ty * 4 + ii) * 65 + tx * 4 + jj] = pp[ii][jj];
  if (di == dj) {
    float* P = Am + (size_t)(i * 64) * n + k * 64;
#pragma unroll
    for (int ii = 0; ii < 4; ++ii)
#pragma unroll
      for (int jj = 0; jj < 4; ++jj) P[(size_t)(ty * 4 + ii) * n + tx * 4 + jj] = pp[ii][jj];
  } else {
#pragma unroll
    for (int ii = 0; ii < 4; ++ii)
#pragma unroll
      for (int jj = 0; jj < 4; ++jj) pp[ii][jj] = 0.0f;
    gemm64<0, 1>(Km + (size_t)(j * 64) * n + k * 64, n, Linv, n, 0, 64, pp, sm);
#pragma unroll
    for (int ii = 0; ii < 4; ++ii)
#pragma unroll
      for (int jj = 0; jj < 4; ++jj) sm.Us[(ty * 4 + ii) * 65 + tx * 4 + jj] = pp[ii][jj];
  }
  __syncthreads();
  float acc[4][4] = {};
  {
    const float* Bsrc = (di == dj) ? sm.Ls : sm.Us;
    for (int l = 0; l < 64; ++l) {
      float a[4], b[4];
#pragma unroll
      for (int ii = 0; ii < 4; ++ii) a[ii] = sm.Ls[(ty * 4 + ii) * 65 + l];
#pragma unroll
      for (int jj = 0; jj < 4; ++jj) b[jj] = Bsrc[(tx * 4 + jj) * 65 + l];
#pragma unroll
      for (int ii = 0; ii < 4; ++ii)
#pragma unroll
        for (int jj = 0; jj < 4; ++jj) acc[ii][jj] = fmaf(a[ii], b[jj], acc[ii][jj]);
    }
  }
  float* C = Km + (size_t)(i * 64) * n + j * 64;
  if (job == 0) {
    __syncthreads();
#pragma unroll
    for (int ii = 0; ii < 4; ++ii)
#pragma unroll
      for (int jj = 0; jj < 4; ++jj)
        sm.Ls[(ty * 4 + ii) * 65 + tx * 4 + jj] =
            C[(size_t)(ty * 4 + ii) * n + tx * 4 + jj] - acc[ii][jj];
    __syncthreads();
    factor64(sm, Am + (size_t)((k + 1) * 64) * n + (k + 1) * 64, n);
  } else {
#pragma unroll
    for (int ii = 0; ii < 4; ++ii)
#pragma unroll
      for (int jj = 0; jj < 4; ++jj)
        C[(size_t)(ty * 4 + ii) * n + tx * 4 + jj] -= acc[ii][jj];
  }
}

// fused trinv level s=64: per pair p, T = L21*A11 then A21 = -A22*T
__global__ __launch_bounds__(256) void k_trinv64(float* ws, int n) {
  __shared__ SMem sm;
  int p = blockIdx.x, m = blockIdx.y, tid = threadIdx.x;
  int tx = tid & 15, ty = tid >> 4;
  float* Am = ws + OFF_A + (size_t)m * 1048576;
  int rb = (2 * p + 1) * 64, cb = 2 * p * 64;
  for (int e = tid; e < 4096; e += 256) {
    int r = e >> 6, c = e & 63;
    sm.Ls[r * 65 + c] = Am[(size_t)(rb + r) * n + cb + c];  // L21
    sm.Us[r * 65 + c] = Am[(size_t)(cb + r) * n + cb + c];  // A11
  }
  __syncthreads();
  float tt[4][4] = {};
  for (int l = 0; l < 64; ++l) {
    float a[4], b[4];
#pragma unroll
    for (int ii = 0; ii < 4; ++ii) a[ii] = sm.Ls[(ty * 4 + ii) * 65 + l];
#pragma unroll
    for (int jj = 0; jj < 4; ++jj) b[jj] = sm.Us[l * 65 + tx * 4 + jj];
#pragma unroll
    for (int ii = 0; ii < 4; ++ii)
#pragma unroll
      for (int jj = 0; jj < 4; ++jj) tt[ii][jj] = fmaf(a[ii], b[jj], tt[ii][jj]);
  }
  __syncthreads();
#pragma unroll
  for (int ii = 0; ii < 4; ++ii)
#pragma unroll
    for (int jj = 0; jj < 4; ++jj) sm.Ls[(ty * 4 + ii) * 65 + tx * 4 + jj] = tt[ii][jj];
  for (int e = tid; e < 4096; e += 256) {
    int r = e >> 6, c = e & 63;
    sm.Us[r * 65 + c] = Am[(size_t)(rb + r) * n + rb + c];  // A22
  }
  __syncthreads();
  float oo[4][4] = {};
  for (int l = 0; l < 64; ++l) {
    float a[4], b[4];
#pragma unroll
    for (int ii = 0; ii < 4; ++ii) a[ii] = sm.Us[(ty * 4 + ii) * 65 + l];
#pragma unroll
    for (int jj = 0; jj < 4; ++jj) b[jj] = sm.Ls[l * 65 + tx * 4 + jj];
#pragma unroll
    for (int ii = 0; ii < 4; ++ii)
#pragma unroll
      for (int jj = 0; jj < 4; ++jj) oo[ii][jj] = fmaf(a[ii], b[jj], oo[ii][jj]);
  }
#pragma unroll
  for (int ii = 0; ii < 4; ++ii)
#pragma unroll
    for (int jj = 0; jj < 4; ++jj)
      Am[(size_t)(rb + ty * 4 + ii) * n + cb + tx * 4 + jj] = -oo[ii][jj];
}

__global__ __launch_bounds__(256) void k_trinvT(float* ws, int s, int n) {
  __shared__ SMem sm;
  int job = blockIdx.x, m = blockIdx.y;
  int tx = threadIdx.x & 15, ty = threadIdx.x >> 4;
  float* Am = ws + OFF_A + (size_t)m * 1048576;
  float* Tm = ws + OFF_T + (size_t)m * 262144;
  int st = s >> 6;
  int p = job / (st * st), rem = job % (st * st);
  int ti = rem / st, tj = rem % st;
  int base = p * 2 * s;
  float acc[4][4] = {};
  gemm64<0, 0>(Am + (size_t)(base + s + ti * 64) * n + base, n,
               Am + (size_t)base * n + base + tj * 64, n, tj * 64, s, acc, sm);
  float* C = Tm + (size_t)p * s * s + (size_t)(ti * 64) * s + tj * 64;
#pragma unroll
  for (int ii = 0; ii < 4; ++ii)
#pragma unroll
    for (int jj = 0; jj < 4; ++jj) C[(size_t)(ty * 4 + ii) * s + tx * 4 + jj] = acc[ii][jj];
}

__global__ __launch_bounds__(256) void k_trinvA(float* ws, int s, int n) {
  __shared__ SMem sm;
  int job = blockIdx.x, m = blockIdx.y;
  int tx = threadIdx.x & 15, ty = threadIdx.x >> 4;
  float* Am = ws + OFF_A + (size_t)m * 1048576;
  const float* Tm = ws + OFF_T + (size_t)m * 262144;
  int st = s >> 6;
  int p = job / (st * st), rem = job % (st * st);
  int ti = rem / st, tj = rem % st;
  int base = p * 2 * s;
  float acc[4][4] = {};
  gemm64<0, 0>(Am + (size_t)(base + s + ti * 64) * n + base + s, n,
               Tm + (size_t)p * s * s + tj * 64, s, 0, (ti + 1) * 64, acc, sm);
  float* C = Am + (size_t)(base + s + ti * 64) * n + base + tj * 64;
#pragma unroll
  for (int ii = 0; ii < 4; ++ii)
#pragma unroll
    for (int jj = 0; jj < 4; ++jj) C[(size_t)(ty * 4 + ii) * n + tx * 4 + jj] = -acc[ii][jj];
}

// syrk + fused alpha (+= G*(y-c)) + fused tr(G)
__global__ __launch_bounds__(256) void k_syrkAT(const float* __restrict__ yc, float* ws, int n) {
  __shared__ SMem sm;
  int job = blockIdx.x, m = blockIdx.y, tid = threadIdx.x;
  int tx = tid & 15, ty = tid >> 4;
  const float* Am = ws + OFF_A + (size_t)m * 1048576;
  float* Gm = ws + (size_t)m * 1048576;
  const float* ym = yc + (size_t)m * NC;
  float* accp = ws + OFF_ACC + m * 8;
  float* al = ws + OFF_ALPHA + (size_t)m * 1024;
  float cm = ws[OFF_SCAL + m * 32 + 15];
  int ib, jb; lt_decode(job, ib, jb);
  if (tid < 64) sm.ai[tid] = ym[ib * 64 + tid] - cm;
  else if (tid < 128) sm.aj[tid - 64] = ym[jb * 64 + tid - 64] - cm;
  float acc[4][4] = {};
  gemm64<1, 0>(Am + ib * 64, n, Am + jb * 64, n, ib * 64, n, acc, sm);
#pragma unroll
  for (int ii = 0; ii < 4; ++ii)
#pragma unroll
    for (int jj = 0; jj < 4; ++jj) {
      int r = ty * 4 + ii, c = tx * 4 + jj;
      Gm[(size_t)(ib * 64 + r) * n + jb * 64 + c] = acc[ii][jj];
      if (ib != jb) Gm[(size_t)(jb * 64 + c) * n + ib * 64 + r] = acc[ii][jj];
    }
  if (ib == jb && tx == ty) {
    atomicAdd(&accp[2], acc[0][0] + acc[1][1] + acc[2][2] + acc[3][3]);
  }
  float rowp[4];
#pragma unroll
  for (int i = 0; i < 4; ++i) {
    float s = 0.0f;
#pragma unroll
    for (int j = 0; j < 4; ++j) s = fmaf(acc[i][j], sm.aj[tx * 4 + j], s);
    rowp[i] = s;
  }
  float colp[4];
  if (ib != jb) {
#pragma unroll
    for (int j = 0; j < 4; ++j) {
      float s = 0.0f;
#pragma unroll
      for (int i = 0; i < 4; ++i) s = fmaf(acc[i][j], sm.ai[ty * 4 + i], s);
      colp[j] = s;
    }
  }
  __syncthreads();
  float* redA = &sm.As[0][0];
  float* redB = &sm.Bs[0][0];
#pragma unroll
  for (int i = 0; i < 4; ++i) redA[(ty * 4 + i) * 16 + tx] = rowp[i];
  if (ib != jb) {
#pragma unroll
    for (int j = 0; j < 4; ++j) redB[(tx * 4 + j) * 16 + ty] = colp[j];
  }
  __syncthreads();
  if (tid < 64) {
    float s = 0.0f;
#pragma unroll
    for (int q = 0; q < 16; ++q) s += redA[tid * 16 + q];
    atomicAdd(&al[ib * 64 + tid], s);
    if (ib != jb) {
      float s2 = 0.0f;
#pragma unroll
      for (int q = 0; q < 16; ++q) s2 += redB[tid * 16 + q];
      atomicAdd(&al[jb * 64 + tid], s2);
    }
  }
}

// reduce: T1 = <G,C>, T2 = alpha^T C alpha (lower-tri, weight 2 off-diag)
__global__ __launch_bounds__(256) void k_reduce(const float* __restrict__ xc, float* ws, int n) {
  __shared__ SMem sm;
  int job = blockIdx.x, m = blockIdx.y, tid = threadIdx.x;
  const float* xm = xc + (size_t)m * NC * 3;
  const float* Gm = ws + (size_t)m * 1048576;
  const float* al = ws + OFF_ALPHA + (size_t)m * 1024;
  float* accp = ws + OFF_ACC + m * 8;
  const float* sT = ws + OFF_SCAL + m * 32;
  float ls = sT[12], os = sT[13];
  float il2 = 1.0f / (ls * ls);
  float c53 = (5.0f / 3.0f) * os / ls;
  int bi, bj; lt_decode(job, bi, bj);
  float w = (bi == bj) ? 1.0f : 2.0f;
  if (tid < 64) {
    int r = bi * 64 + tid;
    sm.xi[tid][0] = xm[r * 3 + 0]; sm.xi[tid][1] = xm[r * 3 + 1]; sm.xi[tid][2] = xm[r * 3 + 2];
    sm.ai[tid] = al[r];
  } else if (tid < 128) {
    int lr = tid - 64; int r = bj * 64 + lr;
    sm.xj[lr][0] = xm[r * 3 + 0]; sm.xj[lr][1] = xm[r * 3 + 1]; sm.xj[lr][2] = xm[r * 3 + 2];
    sm.aj[lr] = al[r];
  }
  __syncthreads();
  float a1 = 0.0f, a2 = 0.0f;
  for (int e = tid; e < 4096; e += 256) {
    int r = e >> 6, c = e & 63;
    float d0 = sm.xi[r][0] - sm.xj[c][0], d1 = sm.xi[r][1] - sm.xj[c][1], d2 = sm.xi[r][2] - sm.xj[c][2];
    float r2 = d0 * d0 + d1 * d1 + d2 * d2;
    float z = fmaxf(r2 * il2, 1e-12f);
    float dd = sqrtf(z);
    float Cv = c53 * z * (1.0f + S5 * dd) * expf(-S5 * dd);
    float g = Gm[(size_t)(bi * 64 + r) * n + bj * 64 + c];
    a1 = fmaf(g, Cv, a1);
    a2 = fmaf(sm.ai[r] * sm.aj[c], Cv, a2);
  }
  a1 *= w; a2 *= w;
  for (int off = 32; off; off >>= 1) { a1 += __shfl_down(a1, off); a2 += __shfl_down(a2, off); }
  int wid = tid >> 6, lane = tid & 63;
  if (lane == 0) { sm.red[wid][0] = a1; sm.red[wid][1] = a2; }
  __syncthreads();
  if (tid == 0) {
    a1 = sm.red[0][0] + sm.red[1][0] + sm.red[2][0] + sm.red[3][0];
    a2 = sm.red[0][1] + sm.red[1][1] + sm.red[2][1] + sm.red[3][1];
    atomicAdd(&accp[0], a1);
    atomicAdd(&accp[1], a2);
  }
}

// prediction
__global__ __launch_bounds__(256) void k_buildKtc(const float* __restrict__ xt,
                                                  const float* __restrict__ xc, float* ws) {
  __shared__ SMem sm;
  int job = blockIdx.x, m = blockIdx.y, tid = threadIdx.x;
  const float* xtm = xt + (size_t)m * NT * 3;
  const float* xm = xc + (size_t)m * NC * 3;
  float* Kt = ws + OFF_KTC + (size_t)m * NT * NC;
  float* Tm = ws + OFF_T + (size_t)m * 262144;  // S1 at Tm, S2 at Tm+NT
  const float* sT = ws + OFF_SCAL + m * 32;
  float ls = sT[12], os = sT[13];
  float il2 = 1.0f / (ls * ls);
  if (job < 2) {
    int z = job * 256 + tid;
    Tm[z] = 0.0f; Tm[NT + z] = 0.0f;
  }
  int ti = job >> 4, tj = job & 15;
  if (tid < 64) {
    int r = ti * 64 + tid;
    sm.xi[tid][0] = xtm[r * 3 + 0]; sm.xi[tid][1] = xtm[r * 3 + 1]; sm.xi[tid][2] = xtm[r * 3 + 2];
  } else if (tid < 128) {
    int lr = tid - 64; int r = tj * 64 + lr;
    sm.xj[lr][0] = xm[r * 3 + 0]; sm.xj[lr][1] = xm[r * 3 + 1]; sm.xj[lr][2] = xm[r * 3 + 2];
  }
  __syncthreads();
  for (int e = tid; e < 4096; e += 256) {
    int r = e >> 6, c = e & 63;
    float d0 = sm.xi[r][0] - sm.xj[c][0], d1 = sm.xi[r][1] - sm.xj[c][1], d2 = sm.xi[r][2] - sm.xj[c][2];
    float r2 = d0 * d0 + d1 * d1 + d2 * d2;
    float z = fmaxf(r2 * il2, 1e-12f);
    float dd = sqrtf(z);
    float kv = os * (1.0f + S5 * dd + (5.0f / 3.0f) * z) * expf(-S5 * dd);
    Kt[(size_t)(ti * 64 + r) * NC + tj * 64 + c] = kv;
  }
}

// W-tile = Ktc*G in-register; fused S1 += Ktc.alpha, S2 += Ktc.W
__global__ __launch_bounds__(256) void k_predW(float* ws) {
  __shared__ SMem sm;
  int job = blockIdx.x, m = blockIdx.y, tid = threadIdx.x;
  int tx = tid & 15, ty = tid >> 4;
  const float* Kt = ws + OFF_KTC + (size_t)m * NT * NC;
  const float* Gm = ws + (size_t)m * 1048576;
  const float* al = ws + OFF_ALPHA + (size_t)m * 1024;
  float* S1 = ws + OFF_T + (size_t)m * 262144;
  float* S2 = S1 + NT;
  int ti = job >> 4, tj = job & 15;
  if (tid < 64) sm.aj[tid] = al[tj * 64 + tid];
  float acc[4][4] = {};
  gemm64<0, 0>(Kt + (size_t)(ti * 64) * NC, NC, Gm + tj * 64, 1024, 0, 1024, acc, sm);
  float s1p[4], s2p[4];
#pragma unroll
  for (int i = 0; i < 4; ++i) {
    float a1 = 0.0f, a2 = 0.0f;
    const float* kr = Kt + (size_t)(ti * 64 + ty * 4 + i) * NC + tj * 64;
#pragma unroll
    for (int j = 0; j < 4; ++j) {
      float kv = kr[tx * 4 + j];
      a1 = fmaf(kv, sm.aj[tx * 4 + j], a1);
      a2 = fmaf(kv, acc[i][j], a2);
    }
    s1p[i] = a1; s2p[i] = a2;
  }
  __syncthreads();
  float* redA = &sm.As[0][0];
  float* redB = &sm.Bs[0][0];
#pragma unroll
  for (int i = 0; i < 4; ++i) {
    redA[(ty * 4 + i) * 16 + tx] = s1p[i];
    redB[(ty * 4 + i) * 16 + tx] = s2p[i];
  }
  __syncthreads();
  if (tid < 64) {
    float a1 = 0.0f, a2 = 0.0f;
#pragma unroll
    for (int q = 0; q < 16; ++q) { a1 += redA[tid * 16 + q]; a2 += redB[tid * 16 + q]; }
    atomicAdd(&S1[ti * 64 + tid], a1);
    atomicAdd(&S2[ti * 64 + tid], a2);
  }
}

__global__ __launch_bounds__(256) void k_final(float* ws, float* out) {
  int m = blockIdx.y, t = blockIdx.x * 256 + threadIdx.x;
  const float* S1 = ws + OFF_T + (size_t)m * 262144;
  const float* S2 = S1 + NT;
  const float* sT = ws + OFF_SCAL + m * 32;
  if (t < NT) {
    out[(size_t)m * NT + t] = sT[15] + S1[t];
    out[(size_t)MM * NT + (size_t)m * NT + t] = sT[13] + sT[14] - S2[t];
  }
}

// ---------------- host: discrete graph pipeline ------------------------------
extern "C" void kernel_launch(void* const* d_in, const int* in_sizes, int n_in,
                              void* d_out, int out_size, void* d_ws, size_t ws_size,
                              hipStream_t stream) {
  const float* xc = (const float*)d_in[0];
  const float* yc = (const float*)d_in[1];
  const float* xt = (const float*)d_in[2];
  float* out = (float*)d_out;
  float* ws = (float*)d_ws;

  k_init<<<dim3(1), dim3(256), 0, stream>>>(ws);

  for (int step = 0; step < 17; ++step) {
    int n = step < 8 ? 512 : 1024;
    int nb = n >> 6;
    if (step > 0) {
      int pn = step <= 8 ? 512 : 1024;
      k_adam<<<dim3(MM), dim3(256), 0, stream>>>(yc, ws, pn, step);
    }
    k_buildK<<<dim3(nb * (nb + 1) / 2, MM), dim3(256), 0, stream>>>(xc, ws, n);
    for (int k = 0; k <= nb - 2; ++k) {
      int t = nb - 1 - k;
      k_trail<<<dim3(t * (t + 1) / 2, MM), dim3(256), 0, stream>>>(ws, k, n);
    }
    k_trinv64<<<dim3(n / 128, MM), dim3(256), 0, stream>>>(ws, n);
    for (int s = 128; s < n; s <<= 1) {
      int st = s >> 6, np = n / (2 * s);
      k_trinvT<<<dim3(np * st * st, MM), dim3(256), 0, stream>>>(ws, s, n);
      k_trinvA<<<dim3(np * st * st, MM), dim3(256), 0, stream>>>(ws, s, n);
    }
    k_syrkAT<<<dim3(nb * (nb + 1) / 2, MM), dim3(256), 0, stream>>>(yc, ws, n);
    if (step < 16) {
      k_reduce<<<dim3(nb * (nb + 1) / 2, MM), dim3(256), 0, stream>>>(xc, ws, n);
    }
  }

  k_buildKtc<<<dim3(128, MM), dim3(256), 0, stream>>>(xt, xc, ws);
  k_predW<<<dim3(128, MM), dim3(256), 0, stream>>>(ws);
  k_final<<<dim3(2, MM), dim3(256), 0, stream>>>(ws, out);

  (void)in_sizes; (void)n_in; (void)out_size; (void)ws_size;
}